// Round 9
// baseline (164.666 us; speedup 1.0000x reference)
//
#include <hip/hip_runtime.h>
#include <hip/hip_bf16.h>

// Problem dims
#define BB 2
#define QQ 40000
#define CC 128
#define NHH 8
#define NPP 4
#define HH 90
#define WW 160
#define HWW (HH*WW)        // 14400
#define BQ (BB*QQ)         // 80000
#define BHW (BB*HWW)       // 28800

typedef __attribute__((ext_vector_type(8))) short short8;
typedef __attribute__((ext_vector_type(4))) unsigned short ushortx4;
typedef __attribute__((ext_vector_type(4))) float f32x4;

static __device__ inline short f2bf(float f) {
    __hip_bfloat16 h = __float2bfloat16(f);
    return __builtin_bit_cast(short, h);
}
static __device__ inline float bfu(unsigned short u) {
    return __builtin_bit_cast(float, ((unsigned)u) << 16);
}

// ---------------------------------------------------------------------------
// Prep: convert weights to bf16, transposed [N][K] layout; concat offset+attn.
// ---------------------------------------------------------------------------
__global__ __launch_bounds__(256) void prep_weights(
    const float* __restrict__ Wv, const float* __restrict__ Wo,
    const float* __restrict__ Wa, const float* __restrict__ Wout,
    const float* __restrict__ bo, const float* __restrict__ ba,
    short* __restrict__ wtv, short* __restrict__ wcat,
    short* __restrict__ woutt, float* __restrict__ bcat)
{
    const int t = blockIdx.x * 256 + threadIdx.x;
    const int stride = gridDim.x * 256;
    for (int i = t; i < 128 * 128; i += stride) {
        int n = i >> 7, k = i & 127;
        wtv[i] = f2bf(Wv[k * 128 + n]);
    }
    for (int i = t; i < 96 * 128; i += stride) {
        int n = i >> 7, k = i & 127;
        float w = (n < 64) ? Wo[k * 64 + n] : Wa[k * 32 + (n - 64)];
        wcat[i] = f2bf(w);
    }
    for (int i = t; i < 128 * 128; i += stride) {
        int n = i >> 7, k = i & 127;
        woutt[i] = f2bf(Wout[k * 128 + n]);
    }
    if (t < 96) bcat[t] = (t < 64) ? bo[t] : ba[t - 64];
}

// ---------------------------------------------------------------------------
// Pipelined MFMA GEMM: Y[rows,N] = X[rows,128] @ W[128,N] + bias
// (used for value-proj and qp-proj)
// ---------------------------------------------------------------------------
template<int N, bool XF32, bool OUT_BF16>
__global__ __launch_bounds__(256, 2) void gemm_pipe(
    const void* __restrict__ Xv, const short* __restrict__ Wt,
    const float* __restrict__ bias, void* __restrict__ Yv, int ntiles)
{
    constexpr int CT = N / 32;
    __shared__ short sW[N * 128];
    __shared__ short sX[128 * 128];
    const int tid = threadIdx.x;

    for (int i = tid; i < N * 16; i += 256) {
        int nn = i >> 4, c8 = (i & 15) * 8;
        short8 wv = reinterpret_cast<const short8*>(Wt)[i];
        *(short8*)((char*)sW + ((nn * 256 + c8 * 2) ^ ((nn & 7) << 4))) = wv;
    }

    const int lane = tid & 63, wid = tid >> 6;
    const int wr = wid >> 1, wc = wid & 1;
    const int l15 = lane & 15, lg = lane >> 4;

    float bvc[CT];
    #pragma unroll
    for (int ct = 0; ct < CT; ++ct) bvc[ct] = bias[wc * (N / 2) + ct * 16 + l15];

    float4 xf[16];
    short8 xb[8];

    int tile = blockIdx.x;
    if (tile < ntiles) {
        if (XF32) {
            const float4* src = reinterpret_cast<const float4*>((const float*)Xv) + (long)tile * 4096;
            #pragma unroll
            for (int j = 0; j < 16; ++j) xf[j] = src[j * 256 + tid];
        } else {
            const short8* src = reinterpret_cast<const short8*>((const short*)Xv) + (long)tile * 2048;
            #pragma unroll
            for (int j = 0; j < 8; ++j) xb[j] = src[j * 256 + tid];
        }
    }

    for (; tile < ntiles; tile += gridDim.x) {
        __syncthreads();
        if (XF32) {
            #pragma unroll
            for (int j = 0; j < 16; ++j) {
                int flat = j * 256 + tid;
                int row = flat >> 5, c4 = flat & 31;
                int byo = (row * 256 + c4 * 8) ^ ((row & 7) << 4);
                short* p = (short*)((char*)sX + byo);
                p[0] = f2bf(xf[j].x); p[1] = f2bf(xf[j].y);
                p[2] = f2bf(xf[j].z); p[3] = f2bf(xf[j].w);
            }
        } else {
            #pragma unroll
            for (int j = 0; j < 8; ++j) {
                int flat = j * 256 + tid;
                int row = flat >> 4, c8 = flat & 15;
                int byo = (row * 256 + c8 * 16) ^ ((row & 7) << 4);
                *(short8*)((char*)sX + byo) = xb[j];
            }
        }
        int nt = tile + gridDim.x;
        if (nt < ntiles) {
            if (XF32) {
                const float4* src = reinterpret_cast<const float4*>((const float*)Xv) + (long)nt * 4096;
                #pragma unroll
                for (int j = 0; j < 16; ++j) xf[j] = src[j * 256 + tid];
            } else {
                const short8* src = reinterpret_cast<const short8*>((const short*)Xv) + (long)nt * 2048;
                #pragma unroll
                for (int j = 0; j < 8; ++j) xb[j] = src[j * 256 + tid];
            }
        }
        __syncthreads();

        f32x4 acc[4][CT] = {};
        #pragma unroll
        for (int ks = 0; ks < 4; ++ks) {
            short8 a[4], b[CT];
            #pragma unroll
            for (int rt = 0; rt < 4; ++rt) {
                int row = wr * 64 + rt * 16 + l15;
                a[rt] = *(const short8*)((const char*)sX +
                        ((row * 256 + ks * 64 + lg * 16) ^ ((row & 7) << 4)));
            }
            #pragma unroll
            for (int ct = 0; ct < CT; ++ct) {
                int n = wc * (N / 2) + ct * 16 + l15;
                b[ct] = *(const short8*)((const char*)sW +
                        ((n * 256 + ks * 64 + lg * 16) ^ ((n & 7) << 4)));
            }
            #pragma unroll
            for (int rt = 0; rt < 4; ++rt)
                #pragma unroll
                for (int ct = 0; ct < CT; ++ct)
                    acc[rt][ct] = __builtin_amdgcn_mfma_f32_16x16x32_bf16(
                        a[rt], b[ct], acc[rt][ct], 0, 0, 0);
        }

        const long r0 = (long)tile * 128;
        #pragma unroll
        for (int rt = 0; rt < 4; ++rt) {
            #pragma unroll
            for (int ct = 0; ct < CT; ++ct) {
                int col = wc * (N / 2) + ct * 16 + l15;
                #pragma unroll
                for (int r = 0; r < 4; ++r) {
                    long row = r0 + wr * 64 + rt * 16 + lg * 4 + r;
                    float val = acc[rt][ct][r] + bvc[ct];
                    if (OUT_BF16) ((short*)Yv)[row * N + col] = f2bf(val);
                    else          ((float*)Yv)[row * N + col] = val;
                }
            }
        }
    }
}

// ---------------------------------------------------------------------------
// Fused sampler + out-projection, occupancy-preserving version.
// LDS = sAgg (32 KB) ONLY -> 4-5 blocks/CU (round-5 failure was 64 KB -> 2).
// Sampling: 16 lanes/query (identical math to round-8's deform_sample16),
// 8 passes cover the block's 128 queries; agg rows -> swizzled LDS bf16.
// Out-proj MFMA reads A-frags from sAgg; B-frags come DIRECTLY from global
// woutt [N][K] (L2-resident 32 KB): woutt[n*128 + ks*32 + lg*8] == what the
// old swizzled sW staging reconstructed. Writes d_out fp32.
// ---------------------------------------------------------------------------
__global__ __launch_bounds__(256, 4) void sample_out2(
    const short* __restrict__ v,      // bf16 [B,HW,128]
    const short* __restrict__ qp,     // bf16 [BQ,96]: [0,64) offsets px, [64,96) logits
    const float* __restrict__ ref,    // fp32 [BQ,2]
    const short* __restrict__ Wt,     // bf16 [128][128] W_out^T (global, L2-resident)
    const float* __restrict__ bias,   // fp32 [128]
    float* __restrict__ out)          // fp32 [BQ,128]
{
    __shared__ short sAgg[128 * 128 / 2 * 2]; // 128 rows x 128 cols bf16 = 32 KB
    const int tid = threadIdx.x;
    const int lane = tid & 63, wid = tid >> 6;
    const long tile0 = (long)blockIdx.x * 128;

    const int q4 = lane >> 4;       // query slot within wave (0..3)
    const int l  = lane & 15;       // dim-chunk: dims [l*8, l*8+8), head = l>>1
    const int h  = l >> 1;

    #pragma unroll
    for (int pass = 0; pass < 8; ++pass) {
        const int lq = wid * 32 + pass * 4 + q4;
        const long bq = tile0 + lq;
        const int bsel = (bq >= QQ) ? 1 : 0;

        const float rx = ref[bq * 2 + 0] * (float)WW - 0.5f;
        const float ry = ref[bq * 2 + 1] * (float)HH - 0.5f;

        const short* qpb = qp + bq * 96;
        ushortx4 lg4 = *reinterpret_cast<const ushortx4*>(qpb + 64 + h * 4);
        float l0 = bfu(lg4[0]), l1 = bfu(lg4[1]), l2 = bfu(lg4[2]), l3 = bfu(lg4[3]);
        float m = fmaxf(fmaxf(l0, l1), fmaxf(l2, l3));
        float e0 = __expf(l0 - m), e1 = __expf(l1 - m);
        float e2 = __expf(l2 - m), e3 = __expf(l3 - m);
        float inv = 1.0f / (e0 + e1 + e2 + e3);
        float aw[4] = { e0 * inv, e1 * inv, e2 * inv, e3 * inv };

        short8 ob = *reinterpret_cast<const short8*>(qpb + h * 8);
        float ofs[8];
        #pragma unroll
        for (int j = 0; j < 8; ++j) ofs[j] = bfu((unsigned short)ob[j]);

        const short* vb = v + (long)bsel * HWW * 128 + l * 8;

        float ac[8] = {0,0,0,0,0,0,0,0};
        #pragma unroll
        for (int p = 0; p < NPP; ++p) {
            float x = rx + ofs[p * 2 + 0];
            float y = ry + ofs[p * 2 + 1];
            float x0f = floorf(x), y0f = floorf(y);
            float wx = x - x0f, wy = y - y0f;
            int ix0 = (int)x0f, iy0 = (int)y0f;
            float wxs[2] = { 1.0f - wx, wx };
            float wys[2] = { 1.0f - wy, wy };
            #pragma unroll
            for (int cy = 0; cy < 2; ++cy) {
                int iy = iy0 + cy;
                bool vy = ((unsigned)iy < (unsigned)HH);
                int iyc = min(max(iy, 0), HH - 1);
                #pragma unroll
                for (int cx = 0; cx < 2; ++cx) {
                    int ix = ix0 + cx;
                    bool vx = ((unsigned)ix < (unsigned)WW);
                    int ixc = min(max(ix, 0), WW - 1);
                    float wgt = (vx && vy) ? (aw[p] * wxs[cx] * wys[cy]) : 0.0f;
                    short8 g = *reinterpret_cast<const short8*>(vb + (iyc * WW + ixc) * 128);
                    #pragma unroll
                    for (int j = 0; j < 8; ++j)
                        ac[j] += wgt * bfu((unsigned short)g[j]);
                }
            }
        }
        short8 pk;
        #pragma unroll
        for (int j = 0; j < 8; ++j) pk[j] = f2bf(ac[j]);
        *(short8*)((char*)sAgg + ((lq * 256 + l * 16) ^ ((lq & 7) << 4))) = pk;
    }
    __syncthreads();

    // out-projection MFMA: out_tile = agg_tile @ Wout + bias
    // A-frags from swizzled sAgg; B-frags straight from global woutt [N][K].
    const int wr = wid >> 1, wc = wid & 1;
    const int l15 = lane & 15, lg = lane >> 4;
    f32x4 acc[4][4] = {};
    #pragma unroll
    for (int ks = 0; ks < 4; ++ks) {
        short8 a[4], b[4];
        #pragma unroll
        for (int rt = 0; rt < 4; ++rt) {
            int row = wr * 64 + rt * 16 + l15;
            a[rt] = *(const short8*)((const char*)sAgg +
                    ((row * 256 + ks * 64 + lg * 16) ^ ((row & 7) << 4)));
        }
        #pragma unroll
        for (int ct = 0; ct < 4; ++ct) {
            int n = wc * 64 + ct * 16 + l15;
            b[ct] = *reinterpret_cast<const short8*>(Wt + n * 128 + ks * 32 + lg * 8);
        }
        #pragma unroll
        for (int rt = 0; rt < 4; ++rt)
            #pragma unroll
            for (int ct = 0; ct < 4; ++ct)
                acc[rt][ct] = __builtin_amdgcn_mfma_f32_16x16x32_bf16(
                    a[rt], b[ct], acc[rt][ct], 0, 0, 0);
    }
    #pragma unroll
    for (int rt = 0; rt < 4; ++rt) {
        #pragma unroll
        for (int ct = 0; ct < 4; ++ct) {
            int col = wc * 64 + ct * 16 + l15;
            float bv = bias[col];
            #pragma unroll
            for (int r = 0; r < 4; ++r) {
                long row = tile0 + wr * 64 + rt * 16 + lg * 4 + r;
                out[row * 128 + col] = acc[rt][ct][r] + bv;
            }
        }
    }
}

extern "C" void kernel_launch(void* const* d_in, const int* in_sizes, int n_in,
                              void* d_out, int out_size, void* d_ws, size_t ws_size,
                              hipStream_t stream) {
    const float* query = (const float*)d_in[0];
    const float* value = (const float*)d_in[1];
    const float* ref   = (const float*)d_in[2];
    const float* Wv    = (const float*)d_in[3];
    const float* bv    = (const float*)d_in[4];
    const float* Wo    = (const float*)d_in[5];
    const float* bo    = (const float*)d_in[6];
    const float* Wa    = (const float*)d_in[7];
    const float* ba    = (const float*)d_in[8];
    const float* Wout  = (const float*)d_in[9];
    const float* bout  = (const float*)d_in[10];
    float* out = (float*)d_out;

    // workspace layout (256B-aligned chunks)
    char* ws = (char*)d_ws;
    short* vbf   = (short*)ws;  ws += (long)BHW * 128 * 2;   // 7.37 MB
    short* wtv   = (short*)ws;  ws += 128 * 128 * 2;         // 32 KB
    short* wcat  = (short*)ws;  ws += 96 * 128 * 2;          // 24 KB
    short* woutt = (short*)ws;  ws += 128 * 128 * 2;         // 32 KB
    float* bcat  = (float*)ws;  ws += 128 * 4;               // 512 B
    short* qpb   = (short*)ws;                               // 15.36 MB (bf16 [BQ,96])

    const int ntV = BHW / 128;   // 225
    const int ntQ = BQ / 128;    // 625
    const int gV = ntV < 512 ? ntV : 512;
    const int gQ = ntQ < 512 ? ntQ : 512;

    // 0) weight prep (bf16 transposed)
    prep_weights<<<64, 256, 0, stream>>>(Wv, Wo, Wa, Wout, bo, ba,
                                         wtv, wcat, woutt, bcat);
    // 1) value projection -> bf16 v
    gemm_pipe<128, true, true><<<gV, 256, 0, stream>>>(value, wtv, bv, vbf, ntV);
    // 2) fused offset+attn projection -> bf16 qp [BQ,96]
    gemm_pipe<96, true, true><<<gQ, 256, 0, stream>>>(query, wcat, bcat, qpb, ntQ);
    // 3) fused sampling + aggregation + output projection -> d_out
    sample_out2<<<ntQ, 256, 0, stream>>>(vbf, qpb, ref, woutt, bout, out);
}

// Round 10
// 161.557 us; speedup vs baseline: 1.0192x; 1.0192x over previous
//
#include <hip/hip_runtime.h>
#include <hip/hip_bf16.h>

// Problem dims
#define BB 2
#define QQ 40000
#define CC 128
#define NHH 8
#define NPP 4
#define HH 90
#define WW 160
#define HWW (HH*WW)        // 14400
#define BQ (BB*QQ)         // 80000
#define BHW (BB*HWW)       // 28800

typedef __attribute__((ext_vector_type(8))) short short8;
typedef __attribute__((ext_vector_type(4))) unsigned short ushortx4;
typedef __attribute__((ext_vector_type(4))) float f32x4;

static __device__ inline short f2bf(float f) {
    __hip_bfloat16 h = __float2bfloat16(f);
    return __builtin_bit_cast(short, h);
}
static __device__ inline float bfu(unsigned short u) {
    return __builtin_bit_cast(float, ((unsigned)u) << 16);
}

// ---------------------------------------------------------------------------
// Prep: convert weights to bf16, transposed [N][K] layout; concat offset+attn.
// ---------------------------------------------------------------------------
__global__ __launch_bounds__(256) void prep_weights(
    const float* __restrict__ Wv, const float* __restrict__ Wo,
    const float* __restrict__ Wa, const float* __restrict__ Wout,
    const float* __restrict__ bo, const float* __restrict__ ba,
    short* __restrict__ wtv, short* __restrict__ wcat,
    short* __restrict__ woutt, float* __restrict__ bcat)
{
    const int t = blockIdx.x * 256 + threadIdx.x;
    const int stride = gridDim.x * 256;
    for (int i = t; i < 128 * 128; i += stride) {
        int n = i >> 7, k = i & 127;
        wtv[i] = f2bf(Wv[k * 128 + n]);
    }
    for (int i = t; i < 96 * 128; i += stride) {
        int n = i >> 7, k = i & 127;
        float w = (n < 64) ? Wo[k * 64 + n] : Wa[k * 32 + (n - 64)];
        wcat[i] = f2bf(w);
    }
    for (int i = t; i < 128 * 128; i += stride) {
        int n = i >> 7, k = i & 127;
        woutt[i] = f2bf(Wout[k * 128 + n]);
    }
    if (t < 96) bcat[t] = (t < 64) ? bo[t] : ba[t - 64];
}

// ---------------------------------------------------------------------------
// GEMM body (shared by gemm_dual roles and gemm_pipe):
// Y[rows,N] = X[rows,128] @ W[128,N] + bias, 2-phase pipelined tile loop.
// smem carve: sW = N*128 bf16 (swizzled), sX = 128*128 bf16 (swizzled).
// ---------------------------------------------------------------------------
template<int N, bool XF32, bool OUT_BF16>
__device__ __forceinline__ void gemm_body(
    char* smem, const void* __restrict__ Xv, const short* __restrict__ Wt,
    const float* __restrict__ bias, void* __restrict__ Yv,
    int ntiles, int bid, int nblocks, int tid)
{
    constexpr int CT = N / 32;
    short* sW = (short*)smem;
    char*  sXb = smem + N * 256;

    for (int i = tid; i < N * 16; i += 256) {
        int nn = i >> 4, c8 = (i & 15) * 8;
        short8 wv = reinterpret_cast<const short8*>(Wt)[i];
        *(short8*)((char*)sW + ((nn * 256 + c8 * 2) ^ ((nn & 7) << 4))) = wv;
    }

    const int lane = tid & 63, wid = tid >> 6;
    const int wr = wid >> 1, wc = wid & 1;
    const int l15 = lane & 15, lg = lane >> 4;

    float bvc[CT];
    #pragma unroll
    for (int ct = 0; ct < CT; ++ct) bvc[ct] = bias[wc * (N / 2) + ct * 16 + l15];

    float4 xf[16];
    short8 xb[8];

    int tile = bid;
    if (tile < ntiles) {
        if (XF32) {
            const float4* src = reinterpret_cast<const float4*>((const float*)Xv) + (long)tile * 4096;
            #pragma unroll
            for (int j = 0; j < 16; ++j) xf[j] = src[j * 256 + tid];
        } else {
            const short8* src = reinterpret_cast<const short8*>((const short*)Xv) + (long)tile * 2048;
            #pragma unroll
            for (int j = 0; j < 8; ++j) xb[j] = src[j * 256 + tid];
        }
    }

    for (; tile < ntiles; tile += nblocks) {
        __syncthreads();
        if (XF32) {
            #pragma unroll
            for (int j = 0; j < 16; ++j) {
                int flat = j * 256 + tid;
                int row = flat >> 5, c4 = flat & 31;
                int byo = (row * 256 + c4 * 8) ^ ((row & 7) << 4);
                short* p = (short*)(sXb + byo);
                p[0] = f2bf(xf[j].x); p[1] = f2bf(xf[j].y);
                p[2] = f2bf(xf[j].z); p[3] = f2bf(xf[j].w);
            }
        } else {
            #pragma unroll
            for (int j = 0; j < 8; ++j) {
                int flat = j * 256 + tid;
                int row = flat >> 4, c8 = flat & 15;
                int byo = (row * 256 + c8 * 16) ^ ((row & 7) << 4);
                *(short8*)(sXb + byo) = xb[j];
            }
        }
        int nt = tile + nblocks;
        if (nt < ntiles) {
            if (XF32) {
                const float4* src = reinterpret_cast<const float4*>((const float*)Xv) + (long)nt * 4096;
                #pragma unroll
                for (int j = 0; j < 16; ++j) xf[j] = src[j * 256 + tid];
            } else {
                const short8* src = reinterpret_cast<const short8*>((const short*)Xv) + (long)nt * 2048;
                #pragma unroll
                for (int j = 0; j < 8; ++j) xb[j] = src[j * 256 + tid];
            }
        }
        __syncthreads();

        f32x4 acc[4][CT] = {};
        #pragma unroll
        for (int ks = 0; ks < 4; ++ks) {
            short8 a[4], b[CT];
            #pragma unroll
            for (int rt = 0; rt < 4; ++rt) {
                int row = wr * 64 + rt * 16 + l15;
                a[rt] = *(const short8*)(sXb +
                        ((row * 256 + ks * 64 + lg * 16) ^ ((row & 7) << 4)));
            }
            #pragma unroll
            for (int ct = 0; ct < CT; ++ct) {
                int n = wc * (N / 2) + ct * 16 + l15;
                b[ct] = *(const short8*)((const char*)sW +
                        ((n * 256 + ks * 64 + lg * 16) ^ ((n & 7) << 4)));
            }
            #pragma unroll
            for (int rt = 0; rt < 4; ++rt)
                #pragma unroll
                for (int ct = 0; ct < CT; ++ct)
                    acc[rt][ct] = __builtin_amdgcn_mfma_f32_16x16x32_bf16(
                        a[rt], b[ct], acc[rt][ct], 0, 0, 0);
        }

        const long r0 = (long)tile * 128;
        #pragma unroll
        for (int rt = 0; rt < 4; ++rt) {
            #pragma unroll
            for (int ct = 0; ct < CT; ++ct) {
                int col = wc * (N / 2) + ct * 16 + l15;
                #pragma unroll
                for (int r = 0; r < 4; ++r) {
                    long row = r0 + wr * 64 + rt * 16 + lg * 4 + r;
                    float val = acc[rt][ct][r] + bvc[ct];
                    if (OUT_BF16) ((short*)Yv)[row * N + col] = f2bf(val);
                    else          ((float*)Yv)[row * N + col] = val;
                }
            }
        }
    }
}

// Dual-role front GEMM: blocks [0,gv) do value-proj (N=128, fp32->bf16);
// blocks [gv, gv+gq) do fused offset+attn proj (N=96, fp32->bf16).
// The two GEMMs are independent -> run concurrently in one dispatch.
__global__ __launch_bounds__(256, 2) void gemm_dual(
    const float* __restrict__ value, const short* __restrict__ wtv,
    const float* __restrict__ bv,    short* __restrict__ vbf, int ntV, int gv,
    const float* __restrict__ query, const short* __restrict__ wcat,
    const float* __restrict__ bcat,  short* __restrict__ qpb, int ntQ, int gq)
{
    __shared__ __align__(16) char smem[128 * 256 + 128 * 256]; // 64 KB max carve
    const int tid = threadIdx.x;
    if ((int)blockIdx.x < gv)
        gemm_body<128, true, true>(smem, value, wtv, bv, vbf, ntV, blockIdx.x, gv, tid);
    else
        gemm_body<96, true, true>(smem, query, wcat, bcat, qpb, ntQ, blockIdx.x - gv, gq, tid);
}

// Out-projection GEMM (bf16 X path), standalone dispatch.
__global__ __launch_bounds__(256, 2) void gemm_out(
    const short* __restrict__ Xb, const short* __restrict__ Wt,
    const float* __restrict__ bias, float* __restrict__ Y, int ntiles)
{
    __shared__ __align__(16) char smem[128 * 256 + 128 * 256];
    gemm_body<128, false, false>(smem, Xb, Wt, bias, Y, ntiles,
                                 blockIdx.x, gridDim.x, threadIdx.x);
}

// ---------------------------------------------------------------------------
// Standalone sampler, 16 lanes per query, no LDS (occupancy-first).
// thread t -> query q = t>>4, dim-chunk l = t&15 (dims [l*8, l*8+8), head l>>1).
// Gathers are 16B/lane, 256B contiguous per (query, corner) -> fully coalesced.
// Writes agg as bf16 [BQ,128] (short8 per lane, 1KB contiguous per wave).
// ---------------------------------------------------------------------------
__global__ __launch_bounds__(256) void deform_sample16(
    const short* __restrict__ v,      // bf16 [B,HW,128]
    const short* __restrict__ qp,     // bf16 [BQ,96]: [0,64) offsets px, [64,96) logits
    const float* __restrict__ ref,    // fp32 [BQ,2]
    short* __restrict__ agg)          // bf16 [BQ,128]
{
    const int t = blockIdx.x * 256 + threadIdx.x;
    const long q = t >> 4;            // query index
    const int l = t & 15;             // dim chunk
    const int h = l >> 1;             // head
    const int bsel = (q >= QQ) ? 1 : 0;

    const float rx = ref[q * 2 + 0] * (float)WW - 0.5f;
    const float ry = ref[q * 2 + 1] * (float)HH - 0.5f;

    const short* qpb = qp + q * 96;
    ushortx4 lg4 = *reinterpret_cast<const ushortx4*>(qpb + 64 + h * 4);
    float l0 = bfu(lg4[0]), l1 = bfu(lg4[1]), l2 = bfu(lg4[2]), l3 = bfu(lg4[3]);
    float m = fmaxf(fmaxf(l0, l1), fmaxf(l2, l3));
    float e0 = __expf(l0 - m), e1 = __expf(l1 - m);
    float e2 = __expf(l2 - m), e3 = __expf(l3 - m);
    float inv = 1.0f / (e0 + e1 + e2 + e3);
    float aw[4] = { e0 * inv, e1 * inv, e2 * inv, e3 * inv };

    short8 ob = *reinterpret_cast<const short8*>(qpb + h * 8);
    float ofs[8];
    #pragma unroll
    for (int j = 0; j < 8; ++j) ofs[j] = bfu((unsigned short)ob[j]);

    const short* vb = v + (long)bsel * HWW * 128 + l * 8;

    float ac[8] = {0,0,0,0,0,0,0,0};
    #pragma unroll
    for (int p = 0; p < NPP; ++p) {
        float x = rx + ofs[p * 2 + 0];
        float y = ry + ofs[p * 2 + 1];
        float x0f = floorf(x), y0f = floorf(y);
        float wx = x - x0f, wy = y - y0f;
        int ix0 = (int)x0f, iy0 = (int)y0f;
        float wxs[2] = { 1.0f - wx, wx };
        float wys[2] = { 1.0f - wy, wy };
        #pragma unroll
        for (int cy = 0; cy < 2; ++cy) {
            int iy = iy0 + cy;
            bool vy = ((unsigned)iy < (unsigned)HH);
            int iyc = min(max(iy, 0), HH - 1);
            #pragma unroll
            for (int cx = 0; cx < 2; ++cx) {
                int ix = ix0 + cx;
                bool vx = ((unsigned)ix < (unsigned)WW);
                int ixc = min(max(ix, 0), WW - 1);
                float wgt = (vx && vy) ? (aw[p] * wxs[cx] * wys[cy]) : 0.0f;
                short8 g = *reinterpret_cast<const short8*>(vb + (iyc * WW + ixc) * 128);
                #pragma unroll
                for (int j = 0; j < 8; ++j)
                    ac[j] += wgt * bfu((unsigned short)g[j]);
            }
        }
    }
    short8 pk;
    #pragma unroll
    for (int j = 0; j < 8; ++j) pk[j] = f2bf(ac[j]);
    *reinterpret_cast<short8*>(agg + q * 128 + l * 8) = pk;
}

extern "C" void kernel_launch(void* const* d_in, const int* in_sizes, int n_in,
                              void* d_out, int out_size, void* d_ws, size_t ws_size,
                              hipStream_t stream) {
    const float* query = (const float*)d_in[0];
    const float* value = (const float*)d_in[1];
    const float* ref   = (const float*)d_in[2];
    const float* Wv    = (const float*)d_in[3];
    const float* bv    = (const float*)d_in[4];
    const float* Wo    = (const float*)d_in[5];
    const float* bo    = (const float*)d_in[6];
    const float* Wa    = (const float*)d_in[7];
    const float* ba    = (const float*)d_in[8];
    const float* Wout  = (const float*)d_in[9];
    const float* bout  = (const float*)d_in[10];
    float* out = (float*)d_out;

    // workspace layout (256B-aligned chunks)
    char* ws = (char*)d_ws;
    short* vbf   = (short*)ws;  ws += (long)BHW * 128 * 2;   // 7.37 MB
    short* wtv   = (short*)ws;  ws += 128 * 128 * 2;         // 32 KB
    short* wcat  = (short*)ws;  ws += 96 * 128 * 2;          // 24 KB
    short* woutt = (short*)ws;  ws += 128 * 128 * 2;         // 32 KB
    float* bcat  = (float*)ws;  ws += 128 * 4;               // 512 B
    short* qpb   = (short*)ws;  ws += (long)BQ * 96 * 2;     // 15.36 MB
    short* aggb  = (short*)ws;                               // 20.48 MB (bf16 [BQ,128])

    const int ntV = BHW / 128;   // 225
    const int ntQ = BQ / 128;    // 625
    const int gV = ntV;                       // 225 (one tile per block)
    const int gQ = ntQ < 512 ? ntQ : 512;     // 512

    // 0) weight prep (bf16 transposed)
    prep_weights<<<64, 256, 0, stream>>>(Wv, Wo, Wa, Wout, bo, ba,
                                         wtv, wcat, woutt, bcat);
    // 1+2) value projection AND fused offset+attn projection, one dispatch
    gemm_dual<<<gV + gQ, 256, 0, stream>>>(value, wtv, bv, vbf, ntV, gV,
                                           query, wcat, bcat, qpb, ntQ, gQ);
    // 3) bilinear sampling + aggregation -> bf16 agg (no LDS, occupancy-first)
    deform_sample16<<<(BQ * 16) / 256, 256, 0, stream>>>(vbf, qpb, ref, aggb);
    // 4) output projection -> d_out
    gemm_out<<<gQ, 256, 0, stream>>>(aggb, woutt, bout, out, ntQ);
}